// Round 2
// baseline (3127.685 us; speedup 1.0000x reference)
//
#include <hip/hip_runtime.h>
#include <math.h>

#define EPS 1e-5f
#define LEAK 0.01f
#define NEG_INF (-3.402823e38f)

__device__ __forceinline__ float sigm(float x){ return 1.0f/(1.0f + __expf(-x)); }
__device__ __forceinline__ float tanhf_(float x){ return 1.0f - 2.0f/(__expf(2.0f*x)+1.0f); }
__device__ __forceinline__ float bnl(float a, float sc, float sh){
    float v = fmaf(a, sc, sh);
    return v < 0.0f ? LEAK*v : v;
}

// ---------- conv block 0: x[256,60,180,1] -> A[Bc,30,90,64] (fused BN+leaky+pool) ----------
__global__ __launch_bounds__(256) void conv0_k(
    const float* __restrict__ x, const float* __restrict__ w,
    const float* __restrict__ cb, const float* __restrict__ g,
    const float* __restrict__ bb, const float* __restrict__ mm,
    const float* __restrict__ mv, float* __restrict__ out, int bbase)
{
    int idx = blockIdx.x*256 + threadIdx.x;
    int co = idx & 63;
    int r = idx >> 6;
    int px = r % 90; r /= 90;
    int py = r % 30; int b0 = r / 30;
    const float* xb = x + (size_t)(bbase + b0)*(60*180);

    float wv[9];
#pragma unroll
    for (int k=0;k<9;k++) wv[k] = w[k*64+co];
    float sc = g[co]*rsqrtf(mv[co]+EPS);
    float sh = fmaf(cb[co]-mm[co], sc, bb[co]);

    float p[4][4];
    int y0 = 2*py-1, x0 = 2*px-1;
#pragma unroll
    for (int rr=0;rr<4;rr++){
        int yy = y0+rr;
#pragma unroll
        for (int cc=0;cc<4;cc++){
            int xx = x0+cc;
            p[rr][cc] = (yy>=0 && yy<60 && xx>=0 && xx<180) ? xb[yy*180+xx] : 0.0f;
        }
    }
    float m = NEG_INF;
#pragma unroll
    for (int dy=0;dy<2;dy++)
#pragma unroll
    for (int dx=0;dx<2;dx++){
        float s = 0.0f;
#pragma unroll
        for (int ky=0;ky<3;ky++)
#pragma unroll
        for (int kx=0;kx<3;kx++)
            s = fmaf(p[dy+ky][dx+kx], wv[ky*3+kx], s);
        m = fmaxf(m, bnl(s, sc, sh));
    }
    out[((b0*30+py)*90+px)*64+co] = m;
}

// ---------- conv block 1: A[Bc,30,90,64] -> B[Bc,15,45,128] ----------
// block: 256 thr = 8 px-pairs x 32 cout-groups(4co). Tile: 16 pooled px per row.
__global__ __launch_bounds__(256) void conv1_k(
    const float* __restrict__ in, const float* __restrict__ w,
    const float* __restrict__ cb, const float* __restrict__ g,
    const float* __restrict__ bb, const float* __restrict__ mm,
    const float* __restrict__ mv, float* __restrict__ out)
{
    __shared__ float ls[4*64*36];   // [row4][cin64][col34 pad36]
    const int xt = blockIdx.x, py = blockIdx.y, b0 = blockIdx.z;
    const int tid = threadIdx.x;
    const int xbase = xt*16;
    {
        const int gy0 = 2*py-1, gx0 = 2*xbase-1;
        const float* ib = in + (size_t)b0*(30*90*64);
        for (int i=0;i<34;i++){
            int idx = tid + i*256;
            int cin = idx & 63;
            int rest = idx >> 6;
            int c = rest % 34, rr = rest / 34;
            int gy = gy0+rr, gx = gx0+c;
            float v = (gy>=0 && gy<30 && gx>=0 && gx<90) ? ib[(gy*90+gx)*64+cin] : 0.0f;
            ls[(rr*64+cin)*36 + c] = v;
        }
    }
    __syncthreads();
    const int g4 = (tid & 31)*4;
    const int p  = tid >> 5;       // 0..7
    float4 acc[2][2][2];           // [pp][dy][dx]
#pragma unroll
    for (int a=0;a<2;a++)
#pragma unroll
    for (int bq=0;bq<2;bq++)
#pragma unroll
    for (int cq=0;cq<2;cq++) acc[a][bq][cq] = make_float4(0.f,0.f,0.f,0.f);

    for (int cin=0;cin<64;cin++){
        float v[4][6];
#pragma unroll
        for (int rr=0;rr<4;rr++){
            const float* rp = &ls[(rr*64+cin)*36 + 4*p];
            float4 a = *(const float4*)rp;
            float2 b2 = *(const float2*)(rp+4);
            v[rr][0]=a.x; v[rr][1]=a.y; v[rr][2]=a.z; v[rr][3]=a.w; v[rr][4]=b2.x; v[rr][5]=b2.y;
        }
        const float* wp = w + cin*128 + g4;
#pragma unroll
        for (int ky=0;ky<3;ky++)
#pragma unroll
        for (int kx=0;kx<3;kx++){
            float4 wv = *(const float4*)(wp + (ky*3+kx)*(64*128));
#pragma unroll
            for (int pp=0;pp<2;pp++)
#pragma unroll
            for (int dy=0;dy<2;dy++)
#pragma unroll
            for (int dx=0;dx<2;dx++){
                float s = v[dy+ky][2*pp+dx+kx];
                float4& A = acc[pp][dy][dx];
                A.x = fmaf(wv.x, s, A.x);
                A.y = fmaf(wv.y, s, A.y);
                A.z = fmaf(wv.z, s, A.z);
                A.w = fmaf(wv.w, s, A.w);
            }
        }
    }
    float4 gv  = *(const float4*)&g[g4];
    float4 mvv = *(const float4*)&mv[g4];
    float4 cbv = *(const float4*)&cb[g4];
    float4 mmv = *(const float4*)&mm[g4];
    float4 bbv = *(const float4*)&bb[g4];
    float4 sc, sh;
    sc.x = gv.x*rsqrtf(mvv.x+EPS); sh.x = fmaf(cbv.x-mmv.x, sc.x, bbv.x);
    sc.y = gv.y*rsqrtf(mvv.y+EPS); sh.y = fmaf(cbv.y-mmv.y, sc.y, bbv.y);
    sc.z = gv.z*rsqrtf(mvv.z+EPS); sh.z = fmaf(cbv.z-mmv.z, sc.z, bbv.z);
    sc.w = gv.w*rsqrtf(mvv.w+EPS); sh.w = fmaf(cbv.w-mmv.w, sc.w, bbv.w);
#pragma unroll
    for (int pp=0;pp<2;pp++){
        int px = xbase + 2*p + pp;
        if (px >= 45) continue;
        float4 m = make_float4(NEG_INF,NEG_INF,NEG_INF,NEG_INF);
#pragma unroll
        for (int dy=0;dy<2;dy++)
#pragma unroll
        for (int dx=0;dx<2;dx++){
            float4 A = acc[pp][dy][dx];
            m.x = fmaxf(m.x, bnl(A.x, sc.x, sh.x));
            m.y = fmaxf(m.y, bnl(A.y, sc.y, sh.y));
            m.z = fmaxf(m.z, bnl(A.z, sc.z, sh.z));
            m.w = fmaxf(m.w, bnl(A.w, sc.w, sh.w));
        }
        *(float4*)&out[(((size_t)b0*15+py)*45+px)*128 + g4] = m;
    }
}

// ---------- conv block 2: B[Bc,15,45,128] -> C[Bc,8,23,128] ----------
// block: 128 thr = 4 px-pairs x 32 cout-groups. Tile: 8 pooled px.
__global__ __launch_bounds__(128) void conv2_k(
    const float* __restrict__ in, const float* __restrict__ w,
    const float* __restrict__ cb, const float* __restrict__ g,
    const float* __restrict__ bb, const float* __restrict__ mm,
    const float* __restrict__ mv, float* __restrict__ out)
{
    __shared__ float ls[4*128*20];  // [row4][cin128][col18 pad20]
    const int xt = blockIdx.x, py = blockIdx.y, b0 = blockIdx.z;
    const int tid = threadIdx.x;
    const int xbase = xt*8;
    {
        const int gy0 = 2*py-1, gx0 = 2*xbase-1;
        const float* ib = in + (size_t)b0*(15*45*128);
        for (int i=0;i<72;i++){
            int idx = tid + i*128;
            int cin = idx & 127;
            int rest = idx >> 7;
            int c = rest % 18, rr = rest / 18;
            int gy = gy0+rr, gx = gx0+c;
            float v = (gy>=0 && gy<15 && gx>=0 && gx<45) ? ib[(gy*45+gx)*128+cin] : 0.0f;
            ls[(rr*128+cin)*20 + c] = v;
        }
    }
    __syncthreads();
    const int g4 = (tid & 31)*4;
    const int p  = tid >> 5;  // 0..3
    float4 acc[2][2][2];
#pragma unroll
    for (int a=0;a<2;a++)
#pragma unroll
    for (int bq=0;bq<2;bq++)
#pragma unroll
    for (int cq=0;cq<2;cq++) acc[a][bq][cq] = make_float4(0.f,0.f,0.f,0.f);

    for (int cin=0;cin<128;cin++){
        float v[4][6];
#pragma unroll
        for (int rr=0;rr<4;rr++){
            const float* rp = &ls[(rr*128+cin)*20 + 4*p];
            float4 a = *(const float4*)rp;
            float2 b2 = *(const float2*)(rp+4);
            v[rr][0]=a.x; v[rr][1]=a.y; v[rr][2]=a.z; v[rr][3]=a.w; v[rr][4]=b2.x; v[rr][5]=b2.y;
        }
        const float* wp = w + cin*128 + g4;
#pragma unroll
        for (int ky=0;ky<3;ky++)
#pragma unroll
        for (int kx=0;kx<3;kx++){
            float4 wv = *(const float4*)(wp + (ky*3+kx)*(128*128));
#pragma unroll
            for (int pp=0;pp<2;pp++)
#pragma unroll
            for (int dy=0;dy<2;dy++)
#pragma unroll
            for (int dx=0;dx<2;dx++){
                float s = v[dy+ky][2*pp+dx+kx];
                float4& A = acc[pp][dy][dx];
                A.x = fmaf(wv.x, s, A.x);
                A.y = fmaf(wv.y, s, A.y);
                A.z = fmaf(wv.z, s, A.z);
                A.w = fmaf(wv.w, s, A.w);
            }
        }
    }
    float4 gv  = *(const float4*)&g[g4];
    float4 mvv = *(const float4*)&mv[g4];
    float4 cbv = *(const float4*)&cb[g4];
    float4 mmv = *(const float4*)&mm[g4];
    float4 bbv = *(const float4*)&bb[g4];
    float4 sc, sh;
    sc.x = gv.x*rsqrtf(mvv.x+EPS); sh.x = fmaf(cbv.x-mmv.x, sc.x, bbv.x);
    sc.y = gv.y*rsqrtf(mvv.y+EPS); sh.y = fmaf(cbv.y-mmv.y, sc.y, bbv.y);
    sc.z = gv.z*rsqrtf(mvv.z+EPS); sh.z = fmaf(cbv.z-mmv.z, sc.z, bbv.z);
    sc.w = gv.w*rsqrtf(mvv.w+EPS); sh.w = fmaf(cbv.w-mmv.w, sc.w, bbv.w);
#pragma unroll
    for (int pp=0;pp<2;pp++){
        int px = xbase + 2*p + pp;
        if (px >= 23) continue;
        float4 m = make_float4(NEG_INF,NEG_INF,NEG_INF,NEG_INF);
#pragma unroll
        for (int dy=0;dy<2;dy++){
            if (2*py+dy >= 15) continue;
#pragma unroll
            for (int dx=0;dx<2;dx++){
                if (2*px+dx >= 45) continue;
                float4 A = acc[pp][dy][dx];
                m.x = fmaxf(m.x, bnl(A.x, sc.x, sh.x));
                m.y = fmaxf(m.y, bnl(A.y, sc.y, sh.y));
                m.z = fmaxf(m.z, bnl(A.z, sc.z, sh.z));
                m.w = fmaxf(m.w, bnl(A.w, sc.w, sh.w));
            }
        }
        *(float4*)&out[(((size_t)b0*8+py)*23+px)*128 + g4] = m;
    }
}

// ---------- conv block 3: C[Bc,8,23,128] -> F[256,4,12,64] ----------
// block: 192 thr = 12 px x 16 cout-groups(4co). Tile: whole pooled row (12 px).
__global__ __launch_bounds__(192) void conv3_k(
    const float* __restrict__ in, const float* __restrict__ w,
    const float* __restrict__ cb, const float* __restrict__ g,
    const float* __restrict__ bb, const float* __restrict__ mm,
    const float* __restrict__ mv, float* __restrict__ out, int bbase)
{
    __shared__ float ls[4*128*28];  // [row4][cin128][col26 pad28]
    const int py = blockIdx.x, b0 = blockIdx.y;
    const int tid = threadIdx.x;
    {
        const int gy0 = 2*py-1;
        const float* ib = in + (size_t)b0*(8*23*128);
        for (int i=0;i<70;i++){
            int idx = tid + i*192;
            if (idx < 13312){
                int cin = idx & 127;
                int rest = idx >> 7;
                int c = rest % 26, rr = rest / 26;
                int gy = gy0+rr, gx = c-1;
                float v = (gy>=0 && gy<8 && gx>=0 && gx<23) ? ib[(gy*23+gx)*128+cin] : 0.0f;
                ls[(rr*128+cin)*28 + c] = v;
            }
        }
    }
    __syncthreads();
    const int g4 = (tid & 15)*4;
    const int px = tid >> 4;   // 0..11
    float4 acc[2][2];
#pragma unroll
    for (int a=0;a<2;a++)
#pragma unroll
    for (int bq=0;bq<2;bq++) acc[a][bq] = make_float4(0.f,0.f,0.f,0.f);

    for (int cin=0;cin<128;cin++){
        float v[4][4];
#pragma unroll
        for (int rr=0;rr<4;rr++){
            const float* rp = &ls[(rr*128+cin)*28 + 2*px];
            float2 a = *(const float2*)rp;
            float2 b2 = *(const float2*)(rp+2);
            v[rr][0]=a.x; v[rr][1]=a.y; v[rr][2]=b2.x; v[rr][3]=b2.y;
        }
        const float* wp = w + cin*64 + g4;
#pragma unroll
        for (int ky=0;ky<3;ky++)
#pragma unroll
        for (int kx=0;kx<3;kx++){
            float4 wv = *(const float4*)(wp + (ky*3+kx)*(128*64));
#pragma unroll
            for (int dy=0;dy<2;dy++)
#pragma unroll
            for (int dx=0;dx<2;dx++){
                float s = v[dy+ky][dx+kx];
                float4& A = acc[dy][dx];
                A.x = fmaf(wv.x, s, A.x);
                A.y = fmaf(wv.y, s, A.y);
                A.z = fmaf(wv.z, s, A.z);
                A.w = fmaf(wv.w, s, A.w);
            }
        }
    }
    float4 gv  = *(const float4*)&g[g4];
    float4 mvv = *(const float4*)&mv[g4];
    float4 cbv = *(const float4*)&cb[g4];
    float4 mmv = *(const float4*)&mm[g4];
    float4 bbv = *(const float4*)&bb[g4];
    float4 sc, sh;
    sc.x = gv.x*rsqrtf(mvv.x+EPS); sh.x = fmaf(cbv.x-mmv.x, sc.x, bbv.x);
    sc.y = gv.y*rsqrtf(mvv.y+EPS); sh.y = fmaf(cbv.y-mmv.y, sc.y, bbv.y);
    sc.z = gv.z*rsqrtf(mvv.z+EPS); sh.z = fmaf(cbv.z-mmv.z, sc.z, bbv.z);
    sc.w = gv.w*rsqrtf(mvv.w+EPS); sh.w = fmaf(cbv.w-mmv.w, sc.w, bbv.w);
    float4 m = make_float4(NEG_INF,NEG_INF,NEG_INF,NEG_INF);
#pragma unroll
    for (int dy=0;dy<2;dy++)
#pragma unroll
    for (int dx=0;dx<2;dx++){
        if (2*px+dx >= 23) continue;
        float4 A = acc[dy][dx];
        m.x = fmaxf(m.x, bnl(A.x, sc.x, sh.x));
        m.y = fmaxf(m.y, bnl(A.y, sc.y, sh.y));
        m.z = fmaxf(m.z, bnl(A.z, sc.z, sh.z));
        m.w = fmaxf(m.w, bnl(A.w, sc.w, sh.w));
    }
    *(float4*)&out[(((size_t)(bbase+b0)*4+py)*12+px)*64 + g4] = m;
}

// ---------- xproj: F[256,4,12,64] -> XP[12,256,512] = x_t @ lW0[:256] + lb0 ----------
__global__ __launch_bounds__(256) void xproj_k(
    const float* __restrict__ feat, const float* __restrict__ lW0,
    const float* __restrict__ lb0, float* __restrict__ xp)
{
    __shared__ float xs[4][256];
    const int r0 = blockIdx.x*4;
    const int tid = threadIdx.x;
#pragma unroll
    for (int q=0;q<4;q++){
        int i = tid + q*256;
        int row = i >> 8, k = i & 255;
        int rr = r0 + row;
        int t = rr >> 8, b = rr & 255;
        xs[row][k] = feat[b*3072 + (k>>6)*768 + t*64 + (k&63)];
    }
    __syncthreads();
    const int j0 = tid, j1 = tid + 256;
    float a0[4] = {0.f,0.f,0.f,0.f}, a1[4] = {0.f,0.f,0.f,0.f};
#pragma unroll 4
    for (int k=0;k<256;k++){
        float w0v = lW0[k*512+j0], w1v = lW0[k*512+j1];
#pragma unroll
        for (int q=0;q<4;q++){
            a0[q] = fmaf(xs[q][k], w0v, a0[q]);
            a1[q] = fmaf(xs[q][k], w1v, a1[q]);
        }
    }
    float bj0 = lb0[j0], bj1 = lb0[j1];
#pragma unroll
    for (int q=0;q<4;q++){
        xp[(r0+q)*512 + j0] = a0[q] + bj0;
        xp[(r0+q)*512 + j1] = a1[q] + bj1;
    }
}

// ---------- persistent 2-layer LSTM + projection: 64 blocks x 4 batch ----------
__global__ __launch_bounds__(256) void lstm_k(
    const float* __restrict__ xp, const float* __restrict__ lW0,
    const float* __restrict__ lW1, const float* __restrict__ lb1,
    const float* __restrict__ Wout, const float* __restrict__ bout,
    float* __restrict__ out)
{
    __shared__ float h0s[4][128];
    __shared__ float h1s[4][128];
    __shared__ float zs[4][512];
    const int tid = threadIdx.x, bg = blockIdx.x;
    const int j0 = tid, j1 = tid + 256;
    const int u = tid & 127;
    const int bl0 = tid >> 7;        // pair 0 batch-lane
    const int bl1 = 2 + (tid >> 7);  // pair 1 batch-lane
    float c0[2] = {0.f, 0.f}, c1[2] = {0.f, 0.f};
    h0s[bl0][u] = 0.f; h0s[bl1][u] = 0.f;
    h1s[bl0][u] = 0.f; h1s[bl1][u] = 0.f;
    const float* Wh0 = lW0 + 256*512;
    const float* Wx1 = lW1;
    const float* Wh1 = lW1 + 128*512;
    const float lbj0 = lb1[j0], lbj1 = lb1[j1];
    __syncthreads();

    for (int t=0;t<12;t++){
        // layer-0 recurrent GEMM: z = xproj + h0 @ Wh0
        const float* xrow = xp + (size_t)(t*256 + bg*4)*512;
        float a0[4], a1[4];
#pragma unroll
        for (int bl=0;bl<4;bl++){ a0[bl] = xrow[bl*512 + j0]; a1[bl] = xrow[bl*512 + j1]; }
#pragma unroll 4
        for (int k=0;k<128;k++){
            float w0v = Wh0[k*512+j0], w1v = Wh0[k*512+j1];
#pragma unroll
            for (int bl=0;bl<4;bl++){
                float h = h0s[bl][k];
                a0[bl] = fmaf(h, w0v, a0[bl]);
                a1[bl] = fmaf(h, w1v, a1[bl]);
            }
        }
#pragma unroll
        for (int bl=0;bl<4;bl++){ zs[bl][j0] = a0[bl]; zs[bl][j1] = a1[bl]; }
        __syncthreads();
        // layer-0 pointwise (gates [i,j,f,o], forget bias 1.0)
        {
            float zi = zs[bl0][u], zj = zs[bl0][128+u], zf = zs[bl0][256+u], zo = zs[bl0][384+u];
            c0[0] = c0[0]*sigm(zf+1.f) + sigm(zi)*tanhf_(zj);
            h0s[bl0][u] = tanhf_(c0[0])*sigm(zo);
            zi = zs[bl1][u]; zj = zs[bl1][128+u]; zf = zs[bl1][256+u]; zo = zs[bl1][384+u];
            c0[1] = c0[1]*sigm(zf+1.f) + sigm(zi)*tanhf_(zj);
            h0s[bl1][u] = tanhf_(c0[1])*sigm(zo);
        }
        __syncthreads();
        // layer-1 GEMM: z = [h0_new, h1] @ lW1 + lb1
#pragma unroll
        for (int bl=0;bl<4;bl++){ a0[bl] = lbj0; a1[bl] = lbj1; }
#pragma unroll 4
        for (int k=0;k<128;k++){
            float w0v = Wx1[k*512+j0], w1v = Wx1[k*512+j1];
#pragma unroll
            for (int bl=0;bl<4;bl++){
                float h = h0s[bl][k];
                a0[bl] = fmaf(h, w0v, a0[bl]);
                a1[bl] = fmaf(h, w1v, a1[bl]);
            }
        }
#pragma unroll 4
        for (int k=0;k<128;k++){
            float w0v = Wh1[k*512+j0], w1v = Wh1[k*512+j1];
#pragma unroll
            for (int bl=0;bl<4;bl++){
                float h = h1s[bl][k];
                a0[bl] = fmaf(h, w0v, a0[bl]);
                a1[bl] = fmaf(h, w1v, a1[bl]);
            }
        }
#pragma unroll
        for (int bl=0;bl<4;bl++){ zs[bl][j0] = a0[bl]; zs[bl][j1] = a1[bl]; }
        __syncthreads();
        // layer-1 pointwise
        {
            float zi = zs[bl0][u], zj = zs[bl0][128+u], zf = zs[bl0][256+u], zo = zs[bl0][384+u];
            c1[0] = c1[0]*sigm(zf+1.f) + sigm(zi)*tanhf_(zj);
            h1s[bl0][u] = tanhf_(c1[0])*sigm(zo);
            zi = zs[bl1][u]; zj = zs[bl1][128+u]; zf = zs[bl1][256+u]; zo = zs[bl1][384+u];
            c1[1] = c1[1]*sigm(zf+1.f) + sigm(zi)*tanhf_(zj);
            h1s[bl1][u] = tanhf_(c1[1])*sigm(zo);
        }
        __syncthreads();
        // projection: logits[t, b, 0:37]
        if (tid < 148){
            int bl = tid/37;
            int n = tid - bl*37;
            float acc = bout[n];
#pragma unroll 4
            for (int k=0;k<128;k++) acc = fmaf(h1s[bl][k], Wout[k*37+n], acc);
            out[(size_t)(t*256 + bg*4 + bl)*37 + n] = acc;
        }
        __syncthreads();
    }
}

extern "C" void kernel_launch(void* const* d_in, const int* in_sizes, int n_in,
                              void* d_out, int out_size, void* d_ws, size_t ws_size,
                              hipStream_t stream) {
    const float* x = (const float*)d_in[0];
    const float *w_[4], *cb_[4], *g_[4], *bb_[4], *mm_[4], *mv_[4];
    for (int i=0;i<4;i++){
        w_[i]  = (const float*)d_in[1+6*i];
        cb_[i] = (const float*)d_in[2+6*i];
        g_[i]  = (const float*)d_in[3+6*i];
        bb_[i] = (const float*)d_in[4+6*i];
        mm_[i] = (const float*)d_in[5+6*i];
        mv_[i] = (const float*)d_in[6+6*i];
    }
    const float* lW0  = (const float*)d_in[25];
    const float* lb0  = (const float*)d_in[26];
    const float* lW1  = (const float*)d_in[27];
    const float* lb1  = (const float*)d_in[28];
    const float* Wout = (const float*)d_in[29];
    const float* bout = (const float*)d_in[30];
    float* out = (float*)d_out;
    float* ws = (float*)d_ws;

    // batch chunk size: pick largest that fits workspace
    // per-batch floats: A 172800 + B 86400 + C 23552 = 282752; persistent: F 786432 + XP 1572864
    int Bc = 64;
    while (Bc > 8 && ((size_t)Bc*282752 + 2359296)*4 > ws_size) Bc >>= 1;
    float* A  = ws;
    float* Bb = A  + (size_t)Bc*172800;
    float* C  = Bb + (size_t)Bc*86400;
    float* F  = C  + (size_t)Bc*23552;
    float* XP = F  + 786432;

    const int nc = 256 / Bc;
    for (int bc=0; bc<nc; bc++){
        int bbase = bc*Bc;
        conv0_k<<<Bc*675, 256, 0, stream>>>(x, w_[0],cb_[0],g_[0],bb_[0],mm_[0],mv_[0], A, bbase);
        conv1_k<<<dim3(3,15,Bc), 256, 0, stream>>>(A, w_[1],cb_[1],g_[1],bb_[1],mm_[1],mv_[1], Bb);
        conv2_k<<<dim3(3,8,Bc), 128, 0, stream>>>(Bb, w_[2],cb_[2],g_[2],bb_[2],mm_[2],mv_[2], C);
        conv3_k<<<dim3(4,Bc), 192, 0, stream>>>(C, w_[3],cb_[3],g_[3],bb_[3],mm_[3],mv_[3], F, bbase);
    }
    xproj_k<<<768, 256, 0, stream>>>(F, lW0, lb0, XP);
    lstm_k<<<64, 256, 0, stream>>>(XP, lW0, lW1, lb1, Wout, bout, out);
}

// Round 3
// 1056.551 us; speedup vs baseline: 2.9603x; 2.9603x over previous
//
#include <hip/hip_runtime.h>
#include <hip/hip_bf16.h>
#include <math.h>

#define EPS 1e-5f
#define LEAK 0.01f
#define NEG_INF (-3.402823e38f)

typedef __attribute__((ext_vector_type(8))) short short8v;
typedef __attribute__((ext_vector_type(4))) float f32x4;

__device__ __forceinline__ float sigm(float x){ return 1.0f/(1.0f + __expf(-x)); }
__device__ __forceinline__ float tanhf_(float x){ return 1.0f - 2.0f/(__expf(2.0f*x)+1.0f); }
__device__ __forceinline__ float bnl(float a, float sc, float sh){
    float v = fmaf(a, sc, sh);
    return v < 0.0f ? LEAK*v : v;
}
__device__ __forceinline__ unsigned short f2bf(float f){
    __hip_bfloat16 h = __float2bfloat16(f);
    return *reinterpret_cast<unsigned short*>(&h);
}
__device__ __forceinline__ float bf2f(unsigned short u){
    return __uint_as_float(((unsigned)u) << 16);
}

// ---------- weight pack: w[3][3][CIN][COUT] f32 -> wp[(9*CIN)/8][COUT][8] bf16 ----------
__global__ __launch_bounds__(256) void pack_k(const float* __restrict__ w,
                                              unsigned short* __restrict__ wp,
                                              int CIN, int COUT){
    int t = blockIdx.x*256 + threadIdx.x;
    int total = 9*CIN*COUT;
    if (t >= total) return;
    int cout = t % COUT, k = t / COUT;           // k = tap*CIN + cin
    float v = w[(size_t)k*COUT + cout];
    wp[(size_t)(k>>3)*COUT*8 + (size_t)cout*8 + (k&7)] = f2bf(v);
}

// ---------- BN fold: sc = g*rsqrt(mv+eps), sh = (cb-mm)*sc + bb ----------
__global__ void bn_k(const float* __restrict__ cb, const float* __restrict__ g,
                     const float* __restrict__ bb, const float* __restrict__ mm,
                     const float* __restrict__ mv, float* __restrict__ sc,
                     float* __restrict__ sh, int n){
    int t = threadIdx.x;
    if (t < n){
        float s = g[t]*rsqrtf(mv[t]+EPS);
        sc[t] = s;
        sh[t] = fmaf(cb[t]-mm[t], s, bb[t]);
    }
}

// ---------- conv block 0: x[256,60,180,1] f32 -> A[Bc,30,90,64] bf16 ----------
__global__ __launch_bounds__(256) void conv0_k(
    const float* __restrict__ x, const float* __restrict__ w,
    const float* __restrict__ cb, const float* __restrict__ g,
    const float* __restrict__ bb, const float* __restrict__ mm,
    const float* __restrict__ mv, unsigned short* __restrict__ out, int bbase)
{
    int idx = blockIdx.x*256 + threadIdx.x;
    int co = idx & 63;
    int r = idx >> 6;
    int px = r % 90; r /= 90;
    int py = r % 30; int b0 = r / 30;
    const float* xb = x + (size_t)(bbase + b0)*(60*180);

    float wv[9];
#pragma unroll
    for (int k=0;k<9;k++) wv[k] = w[k*64+co];
    float sc = g[co]*rsqrtf(mv[co]+EPS);
    float sh = fmaf(cb[co]-mm[co], sc, bb[co]);

    float p[4][4];
    int y0 = 2*py-1, x0 = 2*px-1;
#pragma unroll
    for (int rr=0;rr<4;rr++){
        int yy = y0+rr;
#pragma unroll
        for (int cc=0;cc<4;cc++){
            int xx = x0+cc;
            p[rr][cc] = (yy>=0 && yy<60 && xx>=0 && xx<180) ? xb[yy*180+xx] : 0.0f;
        }
    }
    float m = NEG_INF;
#pragma unroll
    for (int dy=0;dy<2;dy++)
#pragma unroll
    for (int dx=0;dx<2;dx++){
        float s = 0.0f;
#pragma unroll
        for (int ky=0;ky<3;ky++)
#pragma unroll
        for (int kx=0;kx<3;kx++)
            s = fmaf(p[dy+ky][dx+kx], wv[ky*3+kx], s);
        m = fmaxf(m, bnl(s, sc, sh));
    }
    out[((size_t)(b0*30+py)*90+px)*64+co] = f2bf(m);
}

// ---------- MFMA fused conv+BN+leaky+pool ----------
// in:  [Bc][H][W][CIN] bf16, wp: [(9CIN)/8][COUT][8] bf16
// out: [Bc][PH][PW][COUT] bf16, PH=ceil(H/2), PW=ceil(W/2)
// Tile: M = 4 pre-pool rows x 16 cols, N = COUT. 4 waves: wave(wm,wn),
// wm in {0,1} -> rows {2wm,2wm+1} (one pooled row), wn -> COUT/2 couts.
// GEMM: D[pixcol][cout], K = 9*CIN, steps of 32.
template<int CIN,int COUT,int H,int W>
__global__ __launch_bounds__(256) void convmf_k(
    const unsigned short* __restrict__ in, const unsigned short* __restrict__ wp,
    const float* __restrict__ bsc, const float* __restrict__ bsh,
    unsigned short* __restrict__ out)
{
    constexpr int PH = (H+1)/2, PW = (W+1)/2;
    constexpr int NS = (9*CIN)/32;       // K-steps
    constexpr int CSTEPS = CIN/32;       // steps per tap
    constexpr int NREP = COUT/32;        // N fragments per wave
    __shared__ unsigned short wls[2][32*COUT];

    const int tid = threadIdx.x;
    const int lane = tid & 63;
    const int wv = tid >> 6;
    const int wm = wv >> 1, wn = wv & 1;
    const int x0 = blockIdx.x*16, y0 = blockIdx.y*4;
    const int b  = blockIdx.z;
    const unsigned short* inb = in + (size_t)b*H*W*CIN;

    const int l15 = lane & 15, l4 = lane >> 4;
    const int cin0 = l4*8;

    f32x4 acc[2][NREP];
#pragma unroll
    for (int m=0;m<2;m++)
#pragma unroll
    for (int n=0;n<NREP;n++) acc[m][n] = f32x4{0.f,0.f,0.f,0.f};

    auto stage = [&](int s, int buf){
        const unsigned short* src = wp + (size_t)s*32*COUT;
        constexpr int CH = (32*COUT)/(256*8);
#pragma unroll
        for (int i=0;i<CH;i++){
            int e = (tid + i*256)*8;
            *(short8v*)&wls[buf][e] = *(const short8v*)&src[e];
        }
    };

    stage(0, 0);
    __syncthreads();

    for (int s=0; s<NS; ++s){
        const int tap = s / CSTEPS;
        const int ky = tap/3, kx = tap - ky*3;
        const int cbase = (s - tap*CSTEPS)*32 + cin0;
        // A fragments (direct from global; window is L1-resident)
        short8v a[2];
#pragma unroll
        for (int mf=0; mf<2; ++mf){
            const int gy = y0 + 2*wm + mf + ky - 1;
            const int gxl = x0 + l15 + kx - 1;
            const bool okx = (unsigned)gxl < (unsigned)W;
            const int gxc = okx ? gxl : 0;
            short8v v = short8v{0,0,0,0,0,0,0,0};
            if ((unsigned)gy < (unsigned)H){
                short8v t = *(const short8v*)&inb[((size_t)gy*W + gxc)*CIN + cbase];
                v = okx ? t : v;
            }
            a[mf] = v;
        }
        if (s+1 < NS) stage(s+1, (s+1)&1);
        // B fragments from LDS + MFMA
        const unsigned short* wb = &wls[s&1][0];
#pragma unroll
        for (int nf=0; nf<NREP; ++nf){
            const int co = wn*(COUT/2) + nf*16 + l15;
            short8v bfr = *(const short8v*)&wb[(l4*COUT + co)*8];
            acc[0][nf] = __builtin_amdgcn_mfma_f32_16x16x32_bf16(a[0], bfr, acc[0][nf], 0,0,0);
            acc[1][nf] = __builtin_amdgcn_mfma_f32_16x16x32_bf16(a[1], bfr, acc[1][nf], 0,0,0);
        }
        __syncthreads();
    }

    // epilogue: BN + leaky + 2x2 SAME maxpool + bf16 store
    // D layout: pixcol = l4*4 + j (j=0..3), cout = frag base + l15
    const int pr = (y0>>1) + wm;
    if (pr < PH){
        const bool r1 = (y0 + 2*wm + 1) < H;
        const int c0 = x0 + l4*4;
#pragma unroll
        for (int nf=0; nf<NREP; ++nf){
            const int co = wn*(COUT/2) + nf*16 + l15;
            const float scv = bsc[co], shv = bsh[co];
            f32x4 e = acc[0][nf], o = acc[1][nf];
#pragma unroll
            for (int pp=0; pp<2; ++pp){
                const int pc = (x0>>1) + 2*l4 + pp;
                if (pc >= PW) continue;
                const int cb2 = c0 + 2*pp + 1;     // odd column of the pair
                float m = bnl(e[2*pp], scv, shv);
                if (cb2 < W) m = fmaxf(m, bnl(e[2*pp+1], scv, shv));
                if (r1){
                    m = fmaxf(m, bnl(o[2*pp], scv, shv));
                    if (cb2 < W) m = fmaxf(m, bnl(o[2*pp+1], scv, shv));
                }
                out[(((size_t)b*PH + pr)*PW + pc)*COUT + co] = f2bf(m);
            }
        }
    }
}

// ---------- xproj: F[256,4,12,64] bf16 -> XP[12,256,512] f32 = x_t @ lW0[:256] + lb0 ----------
__global__ __launch_bounds__(256) void xproj_k(
    const unsigned short* __restrict__ feat, const float* __restrict__ lW0,
    const float* __restrict__ lb0, float* __restrict__ xp)
{
    __shared__ float xs[4][256];
    const int r0 = blockIdx.x*4;
    const int tid = threadIdx.x;
#pragma unroll
    for (int q=0;q<4;q++){
        int i = tid + q*256;
        int row = i >> 8, k = i & 255;
        int rr = r0 + row;
        int t = rr >> 8, b = rr & 255;
        xs[row][k] = bf2f(feat[(size_t)b*3072 + (k>>6)*768 + t*64 + (k&63)]);
    }
    __syncthreads();
    const int j0 = tid, j1 = tid + 256;
    float a0[4] = {0.f,0.f,0.f,0.f}, a1[4] = {0.f,0.f,0.f,0.f};
#pragma unroll 4
    for (int k=0;k<256;k++){
        float w0v = lW0[k*512+j0], w1v = lW0[k*512+j1];
#pragma unroll
        for (int q=0;q<4;q++){
            a0[q] = fmaf(xs[q][k], w0v, a0[q]);
            a1[q] = fmaf(xs[q][k], w1v, a1[q]);
        }
    }
    float bj0 = lb0[j0], bj1 = lb0[j1];
#pragma unroll
    for (int q=0;q<4;q++){
        xp[(r0+q)*512 + j0] = a0[q] + bj0;
        xp[(r0+q)*512 + j1] = a1[q] + bj1;
    }
}

// ---------- persistent 2-layer LSTM + projection: 64 blocks x 4 batch ----------
__global__ __launch_bounds__(256) void lstm_k(
    const float* __restrict__ xp, const float* __restrict__ lW0,
    const float* __restrict__ lW1, const float* __restrict__ lb1,
    const float* __restrict__ Wout, const float* __restrict__ bout,
    float* __restrict__ out)
{
    __shared__ float h0s[4][128];
    __shared__ float h1s[4][128];
    __shared__ float zs[4][512];
    const int tid = threadIdx.x, bg = blockIdx.x;
    const int j0 = tid, j1 = tid + 256;
    const int u = tid & 127;
    const int bl0 = tid >> 7;
    const int bl1 = 2 + (tid >> 7);
    float c0[2] = {0.f, 0.f}, c1[2] = {0.f, 0.f};
    h0s[bl0][u] = 0.f; h0s[bl1][u] = 0.f;
    h1s[bl0][u] = 0.f; h1s[bl1][u] = 0.f;
    const float* Wh0 = lW0 + 256*512;
    const float* Wx1 = lW1;
    const float* Wh1 = lW1 + 128*512;
    const float lbj0 = lb1[j0], lbj1 = lb1[j1];
    __syncthreads();

    for (int t=0;t<12;t++){
        const float* xrow = xp + (size_t)(t*256 + bg*4)*512;
        float a0[4], a1[4];
#pragma unroll
        for (int bl=0;bl<4;bl++){ a0[bl] = xrow[bl*512 + j0]; a1[bl] = xrow[bl*512 + j1]; }
#pragma unroll 4
        for (int k=0;k<128;k++){
            float w0v = Wh0[k*512+j0], w1v = Wh0[k*512+j1];
#pragma unroll
            for (int bl=0;bl<4;bl++){
                float h = h0s[bl][k];
                a0[bl] = fmaf(h, w0v, a0[bl]);
                a1[bl] = fmaf(h, w1v, a1[bl]);
            }
        }
#pragma unroll
        for (int bl=0;bl<4;bl++){ zs[bl][j0] = a0[bl]; zs[bl][j1] = a1[bl]; }
        __syncthreads();
        {
            float zi = zs[bl0][u], zj = zs[bl0][128+u], zf = zs[bl0][256+u], zo = zs[bl0][384+u];
            c0[0] = c0[0]*sigm(zf+1.f) + sigm(zi)*tanhf_(zj);
            h0s[bl0][u] = tanhf_(c0[0])*sigm(zo);
            zi = zs[bl1][u]; zj = zs[bl1][128+u]; zf = zs[bl1][256+u]; zo = zs[bl1][384+u];
            c0[1] = c0[1]*sigm(zf+1.f) + sigm(zi)*tanhf_(zj);
            h0s[bl1][u] = tanhf_(c0[1])*sigm(zo);
        }
        __syncthreads();
#pragma unroll
        for (int bl=0;bl<4;bl++){ a0[bl] = lbj0; a1[bl] = lbj1; }
#pragma unroll 4
        for (int k=0;k<128;k++){
            float w0v = Wx1[k*512+j0], w1v = Wx1[k*512+j1];
#pragma unroll
            for (int bl=0;bl<4;bl++){
                float h = h0s[bl][k];
                a0[bl] = fmaf(h, w0v, a0[bl]);
                a1[bl] = fmaf(h, w1v, a1[bl]);
            }
        }
#pragma unroll 4
        for (int k=0;k<128;k++){
            float w0v = Wh1[k*512+j0], w1v = Wh1[k*512+j1];
#pragma unroll
            for (int bl=0;bl<4;bl++){
                float h = h1s[bl][k];
                a0[bl] = fmaf(h, w0v, a0[bl]);
                a1[bl] = fmaf(h, w1v, a1[bl]);
            }
        }
#pragma unroll
        for (int bl=0;bl<4;bl++){ zs[bl][j0] = a0[bl]; zs[bl][j1] = a1[bl]; }
        __syncthreads();
        {
            float zi = zs[bl0][u], zj = zs[bl0][128+u], zf = zs[bl0][256+u], zo = zs[bl0][384+u];
            c1[0] = c1[0]*sigm(zf+1.f) + sigm(zi)*tanhf_(zj);
            h1s[bl0][u] = tanhf_(c1[0])*sigm(zo);
            zi = zs[bl1][u]; zj = zs[bl1][128+u]; zf = zs[bl1][256+u]; zo = zs[bl1][384+u];
            c1[1] = c1[1]*sigm(zf+1.f) + sigm(zi)*tanhf_(zj);
            h1s[bl1][u] = tanhf_(c1[1])*sigm(zo);
        }
        __syncthreads();
        if (tid < 148){
            int bl = tid/37;
            int n = tid - bl*37;
            float acc = bout[n];
#pragma unroll 4
            for (int k=0;k<128;k++) acc = fmaf(h1s[bl][k], Wout[k*37+n], acc);
            out[(size_t)(t*256 + bg*4 + bl)*37 + n] = acc;
        }
        __syncthreads();
    }
}

extern "C" void kernel_launch(void* const* d_in, const int* in_sizes, int n_in,
                              void* d_out, int out_size, void* d_ws, size_t ws_size,
                              hipStream_t stream) {
    const float* x = (const float*)d_in[0];
    const float *w_[4], *cb_[4], *g_[4], *bb_[4], *mm_[4], *mv_[4];
    for (int i=0;i<4;i++){
        w_[i]  = (const float*)d_in[1+6*i];
        cb_[i] = (const float*)d_in[2+6*i];
        g_[i]  = (const float*)d_in[3+6*i];
        bb_[i] = (const float*)d_in[4+6*i];
        mm_[i] = (const float*)d_in[5+6*i];
        mv_[i] = (const float*)d_in[6+6*i];
    }
    const float* lW0  = (const float*)d_in[25];
    const float* lb0  = (const float*)d_in[26];
    const float* lW1  = (const float*)d_in[27];
    const float* lb1  = (const float*)d_in[28];
    const float* Wout = (const float*)d_in[29];
    const float* bout = (const float*)d_in[30];
    float* out = (float*)d_out;

    // ---- workspace layout (bytes) ----
    // fixed: XP 6291456 + bn 2560 + F 1572864 + Wp1 147456 + Wp2 294912 + Wp3 147456
    // per-batch (bf16): A 345600 + B 172800 + C 47104 = 565504
    const size_t fixed = 6291456 + 2560 + 1572864 + 147456 + 294912 + 147456;
    int Bc = 64;
    while (Bc > 8 && fixed + (size_t)Bc*565504 > ws_size) Bc >>= 1;

    char* cur = (char*)d_ws;
    float* XP = (float*)cur;               cur += 6291456;
    float* bns = (float*)cur;              cur += 2560;     // sc1,sh1,sc2,sh2,sc3,sh3
    unsigned short* F   = (unsigned short*)cur; cur += 1572864;
    unsigned short* Wp1 = (unsigned short*)cur; cur += 147456;
    unsigned short* Wp2 = (unsigned short*)cur; cur += 294912;
    unsigned short* Wp3 = (unsigned short*)cur; cur += 147456;
    unsigned short* A   = (unsigned short*)cur; cur += (size_t)Bc*345600;
    unsigned short* Bb  = (unsigned short*)cur; cur += (size_t)Bc*172800;
    unsigned short* C   = (unsigned short*)cur;

    // weight pack + BN fold (once)
    pack_k<<<(9*64*128+255)/256, 256, 0, stream>>>(w_[1], Wp1, 64, 128);
    pack_k<<<(9*128*128+255)/256, 256, 0, stream>>>(w_[2], Wp2, 128, 128);
    pack_k<<<(9*128*64+255)/256, 256, 0, stream>>>(w_[3], Wp3, 128, 64);
    bn_k<<<1,128,0,stream>>>(cb_[1],g_[1],bb_[1],mm_[1],mv_[1], bns+0,   bns+128, 128);
    bn_k<<<1,128,0,stream>>>(cb_[2],g_[2],bb_[2],mm_[2],mv_[2], bns+256, bns+384, 128);
    bn_k<<<1,64 ,0,stream>>>(cb_[3],g_[3],bb_[3],mm_[3],mv_[3], bns+512, bns+576, 64);

    const int nc = 256 / Bc;
    for (int bc=0; bc<nc; bc++){
        int bbase = bc*Bc;
        conv0_k<<<Bc*675, 256, 0, stream>>>(x, w_[0],cb_[0],g_[0],bb_[0],mm_[0],mv_[0], A, bbase);
        convmf_k<64,128,30,90><<<dim3(6,8,Bc), 256, 0, stream>>>(A,  Wp1, bns+0,   bns+128, Bb);
        convmf_k<128,128,15,45><<<dim3(3,4,Bc), 256, 0, stream>>>(Bb, Wp2, bns+256, bns+384, C);
        convmf_k<128,64,8,23><<<dim3(2,2,Bc), 256, 0, stream>>>(C,  Wp3, bns+512, bns+576,
                                                                F + (size_t)bbase*3072);
    }
    xproj_k<<<768, 256, 0, stream>>>(F, lW0, lb0, XP);
    lstm_k<<<64, 256, 0, stream>>>(XP, lW0, lW1, lb1, Wout, bout, out);
}